// Round 9
// baseline (27.184 us; speedup 1.0000x reference)
//
#include <hip/hip_runtime.h>
#include <hip/hip_bf16.h>

// Dim indices: N=0, K=1, C=2, P=3, Q=4, R=5, S=6
// DIM_MASK rows  -> Input{N,C,P,Q}=0x1D  Weight{K,C,R,S}=0x66  Output{N,K,P,Q}=0x1B
// REUSE_MASK rows-> Input{K}=0x02        Weight{N,P,Q}=0x19    Output{C,R,S}=0x64

#define BLK 256

__device__ __forceinline__ float fast_rcp(float x) {
    float r;
    asm("v_rcp_f32 %0, %1" : "=v"(r) : "v"(x));
    return r;
}

// Pure-TLP variant: one group per thread, direct global->VGPR float4 loads,
// no LDS staging, no barriers, no inline waitcnt. ~4 waves/SIMD via VGPR count;
// 14 independent loads per thread in flight -> memory system saturates on TLP.
__global__ __launch_bounds__(BLK) void hpm_main(
    const float* __restrict__ T, const float* __restrict__ S,
    const float* __restrict__ PE, const float* __restrict__ BUF,
    double* __restrict__ part, int G, int NB)
{
    const int tid = threadIdx.x;
    const int g   = blockIdx.x * BLK + tid;

    double lat = 0.0, en = 0.0, mis = 0.0;

    if (g < G) {
        // 14 independent 16B loads, issued back-to-back (compiler schedules
        // vmcnt waits at first use).
        float4 tv[7], sv[7];
        const float4* Tp = reinterpret_cast<const float4*>(T) + (size_t)g * 7;
        const float4* Sp = reinterpret_cast<const float4*>(S) + (size_t)g * 7;
        #pragma unroll
        for (int d = 0; d < 7; ++d) tv[d] = Tp[d];
        #pragma unroll
        for (int d = 0; d < 7; ++d) sv[d] = Sp[d];

        const float pe = PE[0];
        const float sq = sqrtf(pe);
        const float b0 = BUF[0], b1 = BUF[1], b2 = BUF[2];
        const float inv_bw_dram   = 1.0f / (100.0f * 1e9f + 1e-9f);
        const float inv_bw_onchip = 1.0f / (sq * 8e9f + 1e-9f);  // 2*sq*4B*1000MHz
        const float epa0 = 1.2f  + 0.002f * b2;
        const float epa1 = 0.52f + 0.01f  * (b1 / sq);
        const float epa2 = 0.18f;
        const float inv_pe = 1.0f / (pe * 1e9f + 1e-9f);

        float fpI[3] = {1.f,1.f,1.f}, fpW[3] = {1.f,1.f,1.f}, fpO[3] = {1.f,1.f,1.f};
        float otI[3] = {1.f,1.f,1.f}, otW[3] = {1.f,1.f,1.f}, otO[3] = {1.f,1.f,1.f};
        float ruI[3] = {1.f,1.f,1.f}, ruW[3] = {1.f,1.f,1.f}, ruO[3] = {1.f,1.f,1.f};
        float macs = 1.f;

        constexpr unsigned IN_D = 0x1D, WT_D = 0x66, OU_D = 0x1B;
        constexpr unsigned IN_R = 0x02, WT_R = 0x19, OU_R = 0x64;

        #pragma unroll
        for (int d = 0; d < 7; ++d) {
            const float4 tt = tv[d];
            const float4 ss = sv[d];

            const float ct0 = tt.x;
            const float ct1 = ct0 * tt.y;
            const float ct2 = ct1 * tt.z;
            const float u0 = tt.x * ss.x, u1 = tt.y * ss.y;
            const float u2 = tt.z * ss.z, u3 = tt.w * ss.w;
            const float cs0 = u0;
            const float cs1 = cs0 * u1;
            const float cs2 = cs1 * u2;
            const float cs3 = cs2 * u3;
            const float st3 = tt.w;
            const float st2 = tt.z * st3;
            const float st1 = tt.y * st2;

            macs *= cs3;

            if ((IN_D >> d) & 1) {
                fpI[0] *= cs0; fpI[1] *= cs1; fpI[2] *= cs2;
                otI[0] *= st1; otI[1] *= st2; otI[2] *= st3;
            }
            if ((WT_D >> d) & 1) {
                fpW[0] *= cs0; fpW[1] *= cs1; fpW[2] *= cs2;
                otW[0] *= st1; otW[1] *= st2; otW[2] *= st3;
            }
            if ((OU_D >> d) & 1) {
                fpO[0] *= cs0; fpO[1] *= cs1; fpO[2] *= cs2;
                otO[0] *= st1; otO[1] *= st2; otO[2] *= st3;
            }
            if ((IN_R >> d) & 1) { ruI[0] *= ct0; ruI[1] *= ct1; ruI[2] *= ct2; }
            if ((WT_R >> d) & 1) { ruW[0] *= ct0; ruW[1] *= ct1; ruW[2] *= ct2; }
            if ((OU_R >> d) & 1) { ruO[0] *= ct0; ruO[1] *= ct1; ruO[2] *= ct2; }
        }

        // v_rcp_f32 (rel err ~1e-7) instead of IEEE divide
        const float acc0 = 4.f * ( fpI[2] * otI[2] * fast_rcp(ruI[2] + 1e-9f)
                                 + fpW[2] * otW[2] * fast_rcp(ruW[2] + 1e-9f)
                                 + fpO[2] * otO[2] * fast_rcp(ruO[2] + 1e-9f) );
        const float acc1 = 4.f * ( fpI[1] * otI[1] * fast_rcp(ruI[1] + 1e-9f)
                                 + fpW[1] * otW[1] * fast_rcp(ruW[1] + 1e-9f)
                                 + fpO[1] * otO[1] * fast_rcp(ruO[1] + 1e-9f) );
        const float acc2 = 4.f * ( fpI[0] * otI[0] * fast_rcp(ruI[0] + 1e-9f)
                                 + fpW[0] * otW[0] * fast_rcp(ruW[0] + 1e-9f)
                                 + fpO[0] * otO[0] * fast_rcp(ruO[0] + 1e-9f) );

        const float ml = fmaxf(acc0 * inv_bw_dram, fmaxf(acc1, acc2) * inv_bw_onchip);
        const float cl = macs * inv_pe;
        lat = (double)fmaxf(cl, ml);

        en = (double)(macs * 0.56f + (acc0 * epa0 + acc1 * epa1 + acc2 * epa2) * 0.25f);

        const float c = 4.f / 1024.f;
        const float r0 = (fpI[0] + fpW[0] + fpO[0]) * c;
        const float r1 = (fpI[1] + fpW[1] + fpO[1]) * c;
        const float r2 = (fpI[2] + fpW[2] + fpO[2]) * c;
        const float d0 = fmaxf(r0 - b0, 0.f);
        const float d1 = fmaxf(r1 - b1, 0.f);
        const float d2 = fmaxf(r2 - b2, 0.f);
        mis = (double)d0 * d0 + (double)d1 * d1 + (double)d2 * d2;
    }

    // wave (64-lane) shuffle reduction
    #pragma unroll
    for (int off = 32; off > 0; off >>= 1) {
        lat += __shfl_down(lat, off);
        en  += __shfl_down(en,  off);
        mis += __shfl_down(mis, off);
    }

    __shared__ double sred[3][4];
    const int wid  = tid >> 6;
    const int lane = tid & 63;
    if (lane == 0) { sred[0][wid] = lat; sred[1][wid] = en; sred[2][wid] = mis; }
    __syncthreads();

    if (tid == 0) {
        double L = 0.0, E = 0.0, M = 0.0;
        #pragma unroll
        for (int v = 0; v < 4; ++v) { L += sred[0][v]; E += sred[1][v]; M += sred[2][v]; }
        // private per-block slots, plane-major; NO atomics, NO fences.
        part[0 * NB + blockIdx.x] = L;
        part[1 * NB + blockIdx.x] = E;
        part[2 * NB + blockIdx.x] = M;
    }
}

__global__ __launch_bounds__(256) void hpm_final(
    const double* __restrict__ part, int NB,
    const float* __restrict__ PE, const float* __restrict__ BUF,
    float* __restrict__ out)
{
    const int tid = threadIdx.x;
    double L = 0.0, E = 0.0, M = 0.0;
    for (int i = tid; i < NB; i += 256) {
        L += part[0 * NB + i];
        E += part[1 * NB + i];
        M += part[2 * NB + i];
    }

    #pragma unroll
    for (int off = 32; off > 0; off >>= 1) {
        L += __shfl_down(L, off);
        E += __shfl_down(E, off);
        M += __shfl_down(M, off);
    }

    __shared__ double sred[3][4];
    const int wid  = tid >> 6;
    const int lane = tid & 63;
    if (lane == 0) { sred[0][wid] = L; sred[1][wid] = E; sred[2][wid] = M; }
    __syncthreads();

    if (tid == 0) {
        double Lt = 0.0, Et = 0.0, Mt = 0.0;
        #pragma unroll
        for (int v = 0; v < 4; ++v) { Lt += sred[0][v]; Et += sred[1][v]; Mt += sred[2][v]; }
        out[0] = (float)Lt;                                           // total_latency
        out[1] = (float)Et;                                           // total_energy
        out[2] = PE[0] * 0.01f + (BUF[0] + BUF[1] + BUF[2]) * 0.005f; // area
        out[3] = (float)Mt;                                           // total_mismatch
    }
}

extern "C" void kernel_launch(void* const* d_in, const int* in_sizes, int n_in,
                              void* d_out, int out_size, void* d_ws, size_t ws_size,
                              hipStream_t stream) {
    const float* T   = (const float*)d_in[0];   // temporal_factors [G,7,4]
    const float* S   = (const float*)d_in[1];   // spatial_factors  [G,7,4]
    const float* PE  = (const float*)d_in[2];   // num_pes [1]
    const float* BUF = (const float*)d_in[3];   // buffer_sizes_kb [3]
    float* out = (float*)d_out;
    double* ws = (double*)d_ws;

    const int G  = in_sizes[0] / 28;
    const int NB = (G + BLK - 1) / BLK;

    hipLaunchKernelGGL(hpm_main, dim3(NB), dim3(BLK), 0, stream,
                       T, S, PE, BUF, ws, G, NB);
    hipLaunchKernelGGL(hpm_final, dim3(1), dim3(256), 0, stream,
                       ws, NB, PE, BUF, out);
}

// Round 10
// 25.820 us; speedup vs baseline: 1.0528x; 1.0528x over previous
//
#include <hip/hip_runtime.h>
#include <hip/hip_bf16.h>

// Dim indices: N=0, K=1, C=2, P=3, Q=4, R=5, S=6
// DIM_MASK rows  -> Input{N,C,P,Q}=0x1D  Weight{K,C,R,S}=0x66  Output{N,K,P,Q}=0x1B
// REUSE_MASK rows-> Input{K}=0x02        Weight{N,P,Q}=0x19    Output{C,R,S}=0x64

typedef const __attribute__((address_space(1))) void* gptr_t;
typedef __attribute__((address_space(3))) void* lptr_t;

#define BLK   256
#define NBK   256                 // persistent: 1 block/CU
#define WPB   4                   // waves per block
#define NWAVE (NBK * WPB)         // 1024 self-paced wave streams
#define TGRP  64                  // groups per wave-tile (= 1 lane per group)

__device__ __forceinline__ float fast_rcp(float x) {
    float r;
    asm("v_rcp_f32 %0, %1" : "=v"(r) : "v"(x));
    return r;
}

__global__ __launch_bounds__(BLK) void hpm_main(
    const float* __restrict__ T, const float* __restrict__ S,
    const float* __restrict__ PE, const float* __restrict__ BUF,
    double* __restrict__ part, int G)
{
    // per-wave private: [wave][buf][T/S][64 groups * 28 floats] = 4*2*2*7KB = 112 KB
    __shared__ float lds[WPB][2][2][TGRP * 28];

    const int tid  = threadIdx.x;
    const int w    = tid >> 6;
    const int lane = tid & 63;
    const int W    = blockIdx.x * WPB + w;          // global wave id
    const int NT   = G / TGRP;                      // full 64-group tiles
    const int cnt  = (NT > W) ? ((NT - 1 - W) / NWAVE + 1) : 0;

    // block-uniform scalars; drain their loads so they can't perturb vmcnt counting
    const float pe = PE[0];
    const float sq = sqrtf(pe);
    const float b0 = BUF[0], b1 = BUF[1], b2 = BUF[2];
    const float inv_bw_dram   = 1.0f / (100.0f * 1e9f + 1e-9f);
    const float inv_bw_onchip = 1.0f / (sq * 8e9f + 1e-9f);   // 2*sq*4B*1000MHz in B/s
    const float epa0 = 1.2f  + 0.002f * b2;
    const float epa1 = 0.52f + 0.01f  * (b1 / sq);
    const float epa2 = 0.18f;
    const float inv_pe = 1.0f / (pe * 1e9f + 1e-9f);
    asm volatile("s_waitcnt vmcnt(0) lgkmcnt(0)" ::: "memory");

    constexpr unsigned IN_D = 0x1D, WT_D = 0x66, OU_D = 0x1B;
    constexpr unsigned IN_R = 0x02, WT_R = 0x19, OU_R = 0x64;

    auto issue = [&](int t, int buf) {   // 14 VMEM instrs per wave per tile
        const float* gT = T + (size_t)t * (TGRP * 28);
        const float* gS = S + (size_t)t * (TGRP * 28);
        #pragma unroll
        for (int k = 0; k < 7; ++k) {
            const int fo = (k * 64 + lane) * 4;        // per-lane float offset
            __builtin_amdgcn_global_load_lds((gptr_t)(gT + fo),
                                             (lptr_t)&lds[w][buf][0][k * 256], 16, 0, 0);
            __builtin_amdgcn_global_load_lds((gptr_t)(gS + fo),
                                             (lptr_t)&lds[w][buf][1][k * 256], 16, 0, 0);
        }
    };

    double latA = 0.0, enA = 0.0, misA = 0.0;

    auto accumulate = [&](const float4* tv, const float4* sv) {
        float fpI[3] = {1.f,1.f,1.f}, fpW[3] = {1.f,1.f,1.f}, fpO[3] = {1.f,1.f,1.f};
        float otI[3] = {1.f,1.f,1.f}, otW[3] = {1.f,1.f,1.f}, otO[3] = {1.f,1.f,1.f};
        float ruI[3] = {1.f,1.f,1.f}, ruW[3] = {1.f,1.f,1.f}, ruO[3] = {1.f,1.f,1.f};
        float macs = 1.f;

        #pragma unroll
        for (int d = 0; d < 7; ++d) {
            const float4 tt = tv[d];
            const float4 ss = sv[d];

            const float ct0 = tt.x;
            const float ct1 = ct0 * tt.y;
            const float ct2 = ct1 * tt.z;
            const float u0 = tt.x * ss.x, u1 = tt.y * ss.y;
            const float u2 = tt.z * ss.z, u3 = tt.w * ss.w;
            const float cs0 = u0;
            const float cs1 = cs0 * u1;
            const float cs2 = cs1 * u2;
            const float cs3 = cs2 * u3;
            const float st3 = tt.w;
            const float st2 = tt.z * st3;
            const float st1 = tt.y * st2;

            macs *= cs3;

            if ((IN_D >> d) & 1) {
                fpI[0] *= cs0; fpI[1] *= cs1; fpI[2] *= cs2;
                otI[0] *= st1; otI[1] *= st2; otI[2] *= st3;
            }
            if ((WT_D >> d) & 1) {
                fpW[0] *= cs0; fpW[1] *= cs1; fpW[2] *= cs2;
                otW[0] *= st1; otW[1] *= st2; otW[2] *= st3;
            }
            if ((OU_D >> d) & 1) {
                fpO[0] *= cs0; fpO[1] *= cs1; fpO[2] *= cs2;
                otO[0] *= st1; otO[1] *= st2; otO[2] *= st3;
            }
            if ((IN_R >> d) & 1) { ruI[0] *= ct0; ruI[1] *= ct1; ruI[2] *= ct2; }
            if ((WT_R >> d) & 1) { ruW[0] *= ct0; ruW[1] *= ct1; ruW[2] *= ct2; }
            if ((OU_R >> d) & 1) { ruO[0] *= ct0; ruO[1] *= ct1; ruO[2] *= ct2; }
        }

        // v_rcp_f32 (rel err ~1e-7) instead of IEEE divide: 1 instr vs ~10
        const float acc0 = 4.f * ( fpI[2] * otI[2] * fast_rcp(ruI[2] + 1e-9f)
                                 + fpW[2] * otW[2] * fast_rcp(ruW[2] + 1e-9f)
                                 + fpO[2] * otO[2] * fast_rcp(ruO[2] + 1e-9f) );
        const float acc1 = 4.f * ( fpI[1] * otI[1] * fast_rcp(ruI[1] + 1e-9f)
                                 + fpW[1] * otW[1] * fast_rcp(ruW[1] + 1e-9f)
                                 + fpO[1] * otO[1] * fast_rcp(ruO[1] + 1e-9f) );
        const float acc2 = 4.f * ( fpI[0] * otI[0] * fast_rcp(ruI[0] + 1e-9f)
                                 + fpW[0] * otW[0] * fast_rcp(ruW[0] + 1e-9f)
                                 + fpO[0] * otO[0] * fast_rcp(ruO[0] + 1e-9f) );

        const float ml = fmaxf(acc0 * inv_bw_dram, fmaxf(acc1, acc2) * inv_bw_onchip);
        const float cl = macs * inv_pe;
        latA += (double)fmaxf(cl, ml);

        enA += (double)(macs * 0.56f + (acc0 * epa0 + acc1 * epa1 + acc2 * epa2) * 0.25f);

        const float c = 4.f / 1024.f;
        const float r0 = (fpI[0] + fpW[0] + fpO[0]) * c;
        const float r1 = (fpI[1] + fpW[1] + fpO[1]) * c;
        const float r2 = (fpI[2] + fpW[2] + fpO[2]) * c;
        const float d0 = fmaxf(r0 - b0, 0.f);
        const float d1 = fmaxf(r1 - b1, 0.f);
        const float d2 = fmaxf(r2 - b2, 0.f);
        misA += (double)d0 * d0 + (double)d1 * d1 + (double)d2 * d2;
    };

    // ---- 2-deep per-wave pipeline, NO barriers in the hot loop ----
    if (cnt > 0) issue(W, 0);
    if (cnt > 1) issue(W + NWAVE, 1);

    for (int i = 0; i < cnt; ++i) {
        // wait for tile i's 14 loads; keep tile i+1's 14 in flight (per-wave counter)
        if (i + 1 < cnt) asm volatile("s_waitcnt vmcnt(14)" ::: "memory");
        else             asm volatile("s_waitcnt vmcnt(0)"  ::: "memory");

        const int buf = i & 1;
        float4 tv[7], sv[7];
        {
            const float4* Tl = reinterpret_cast<const float4*>(&lds[w][buf][0][lane * 28]);
            const float4* Sl = reinterpret_cast<const float4*>(&lds[w][buf][1][lane * 28]);
            #pragma unroll
            for (int d = 0; d < 7; ++d) { tv[d] = Tl[d]; sv[d] = Sl[d]; }
        }
        // reads must land before DMA overwrites this buffer (no barrier needed: wave-private)
        asm volatile("s_waitcnt lgkmcnt(0)" ::: "memory");
        __builtin_amdgcn_sched_barrier(0);

        if (i + 2 < cnt) issue(W + (i + 2) * NWAVE, buf);

        accumulate(tv, sv);
    }

    // ---- tail: last global wave handles G % 64 groups (vmcnt fully drained) ----
    if (W == NWAVE - 1) {
        const int g = NT * TGRP + lane;
        if (g < G) {
            float4 tv[7], sv[7];
            const float4* Tp = reinterpret_cast<const float4*>(T) + (size_t)g * 7;
            const float4* Sp = reinterpret_cast<const float4*>(S) + (size_t)g * 7;
            #pragma unroll
            for (int d = 0; d < 7; ++d) { tv[d] = Tp[d]; sv[d] = Sp[d]; }
            accumulate(tv, sv);
        }
    }

    // ---- wave (64-lane) shuffle reduction ----
    #pragma unroll
    for (int off = 32; off > 0; off >>= 1) {
        latA += __shfl_down(latA, off);
        enA  += __shfl_down(enA,  off);
        misA += __shfl_down(misA, off);
    }

    __shared__ double sred[3][WPB];
    if (lane == 0) { sred[0][w] = latA; sred[1][w] = enA; sred[2][w] = misA; }
    __syncthreads();

    if (tid == 0) {
        double L = 0.0, E = 0.0, M = 0.0;
        #pragma unroll
        for (int v = 0; v < WPB; ++v) { L += sred[0][v]; E += sred[1][v]; M += sred[2][v]; }
        // private per-block slots, plane-major; NO atomics, NO fences.
        part[0 * NBK + blockIdx.x] = L;
        part[1 * NBK + blockIdx.x] = E;
        part[2 * NBK + blockIdx.x] = M;
    }
}

__global__ __launch_bounds__(256) void hpm_final(
    const double* __restrict__ part,
    const float* __restrict__ PE, const float* __restrict__ BUF,
    float* __restrict__ out)
{
    const int tid = threadIdx.x;
    double L = 0.0, E = 0.0, M = 0.0;
    if (tid < NBK) {
        L = part[0 * NBK + tid];
        E = part[1 * NBK + tid];
        M = part[2 * NBK + tid];
    }

    #pragma unroll
    for (int off = 32; off > 0; off >>= 1) {
        L += __shfl_down(L, off);
        E += __shfl_down(E, off);
        M += __shfl_down(M, off);
    }

    __shared__ double sred[3][4];
    const int wid  = tid >> 6;
    const int lane = tid & 63;
    if (lane == 0) { sred[0][wid] = L; sred[1][wid] = E; sred[2][wid] = M; }
    __syncthreads();

    if (tid == 0) {
        double Lt = 0.0, Et = 0.0, Mt = 0.0;
        #pragma unroll
        for (int v = 0; v < 4; ++v) { Lt += sred[0][v]; Et += sred[1][v]; Mt += sred[2][v]; }
        out[0] = (float)Lt;                                           // total_latency
        out[1] = (float)Et;                                           // total_energy
        out[2] = PE[0] * 0.01f + (BUF[0] + BUF[1] + BUF[2]) * 0.005f; // area
        out[3] = (float)Mt;                                           // total_mismatch
    }
}

extern "C" void kernel_launch(void* const* d_in, const int* in_sizes, int n_in,
                              void* d_out, int out_size, void* d_ws, size_t ws_size,
                              hipStream_t stream) {
    const float* T   = (const float*)d_in[0];   // temporal_factors [G,7,4]
    const float* S   = (const float*)d_in[1];   // spatial_factors  [G,7,4]
    const float* PE  = (const float*)d_in[2];   // num_pes [1]
    const float* BUF = (const float*)d_in[3];   // buffer_sizes_kb [3]
    float* out = (float*)d_out;
    double* ws = (double*)d_ws;

    const int G = in_sizes[0] / 28;

    hipLaunchKernelGGL(hpm_main, dim3(NBK), dim3(BLK), 0, stream,
                       T, S, PE, BUF, ws, G);
    hipLaunchKernelGGL(hpm_final, dim3(1), dim3(256), 0, stream,
                       ws, PE, BUF, out);
}